// Round 3
// baseline (1041.316 us; speedup 1.0000x reference)
//
#include <hip/hip_runtime.h>

#define D_MODEL 512
#define DINNER  1024
#define DSTATE  64
#define DTRANK  32
#define BSZ     2
#define NLEN    2048
#define NROWS   (BSZ*NLEN)   // 4096
#define XDBL_W  (DTRANK + 2*DSTATE)  // 160

// ---------------- LayerNorm: one wave per row ----------------
__global__ __launch_bounds__(256) void ln_kernel(const float* __restrict__ x,
        const float* __restrict__ w, const float* __restrict__ bvec,
        float* __restrict__ xn) {
    const int wid = threadIdx.x >> 6, lane = threadIdx.x & 63;
    const int row = (blockIdx.x << 2) + wid;
    const float4* xp = (const float4*)(x + (size_t)row * D_MODEL);
    float4 v0 = xp[lane], v1 = xp[lane + 64];
    float s = v0.x + v0.y + v0.z + v0.w + v1.x + v1.y + v1.z + v1.w;
    float q = v0.x*v0.x + v0.y*v0.y + v0.z*v0.z + v0.w*v0.w
            + v1.x*v1.x + v1.y*v1.y + v1.z*v1.z + v1.w*v1.w;
    #pragma unroll
    for (int m = 32; m; m >>= 1) { s += __shfl_xor(s, m); q += __shfl_xor(q, m); }
    const float mean = s * (1.f / D_MODEL);
    const float var  = q * (1.f / D_MODEL) - mean * mean;
    const float rstd = rsqrtf(var + 1e-5f);
    const float4* wp = (const float4*)w;
    const float4* bp = (const float4*)bvec;
    float4 w0 = wp[lane], w1 = wp[lane + 64], b0 = bp[lane], b1 = bp[lane + 64];
    float4 o0, o1;
    o0.x = (v0.x - mean) * rstd * w0.x + b0.x;
    o0.y = (v0.y - mean) * rstd * w0.y + b0.y;
    o0.z = (v0.z - mean) * rstd * w0.z + b0.z;
    o0.w = (v0.w - mean) * rstd * w0.w + b0.w;
    o1.x = (v1.x - mean) * rstd * w1.x + b1.x;
    o1.y = (v1.y - mean) * rstd * w1.y + b1.y;
    o1.z = (v1.z - mean) * rstd * w1.z + b1.z;
    o1.w = (v1.w - mean) * rstd * w1.w + b1.w;
    float4* op = (float4*)(xn + (size_t)row * D_MODEL);
    op[lane] = o0; op[lane + 64] = o1;
}

// ------------- generic NT SGEMM: C(M,N) = A(M,K) * B(N,K)^T -------------
// BM=128, BN=64, BK=8; 256 threads; 8x4 micro-tile; register prefetch of next
// K-tile issued before the compute loop (overlaps global latency with FMAs).
__global__ __launch_bounds__(256) void gemm_nt(const float* __restrict__ A,
        const float* __restrict__ B, int M, int N, int K,
        float* __restrict__ out0, float* __restrict__ out1, int split) {
    __shared__ float sA[8][132];
    __shared__ float sB[8][68];
    const int tid = threadIdx.x;
    const int m0 = blockIdx.y * 128, n0 = blockIdx.x * 64;
    const int lr = tid >> 1, lc = (tid & 1) << 2;
    const int ty = tid >> 4, tx = tid & 15;
    float acc[2][4][4] = {};
    const float* Aptr = A + (size_t)(m0 + lr) * K + lc;
    const bool bvalid = (tid < 128) && (n0 + lr < N);
    const float* Bptr = B + (size_t)(bvalid ? (n0 + lr) : 0) * K + lc;
    float4 av = *(const float4*)Aptr;
    float4 bv = bvalid ? *(const float4*)Bptr : make_float4(0.f, 0.f, 0.f, 0.f);
    for (int k0 = 0; k0 < K; k0 += 8) {
        __syncthreads();
        sA[lc + 0][lr] = av.x; sA[lc + 1][lr] = av.y;
        sA[lc + 2][lr] = av.z; sA[lc + 3][lr] = av.w;
        if (tid < 128) {
            sB[lc + 0][lr] = bv.x; sB[lc + 1][lr] = bv.y;
            sB[lc + 2][lr] = bv.z; sB[lc + 3][lr] = bv.w;
        }
        __syncthreads();
        if (k0 + 8 < K) {
            av = *(const float4*)(Aptr + k0 + 8);
            if (bvalid) bv = *(const float4*)(Bptr + k0 + 8);
        }
        #pragma unroll
        for (int kk = 0; kk < 8; ++kk) {
            float4 a0 = *(const float4*)&sA[kk][ty << 2];
            float4 a1 = *(const float4*)&sA[kk][64 + (ty << 2)];
            float4 bb = *(const float4*)&sB[kk][tx << 2];
            const float aa[2][4] = {{a0.x, a0.y, a0.z, a0.w}, {a1.x, a1.y, a1.z, a1.w}};
            const float bbv[4] = {bb.x, bb.y, bb.z, bb.w};
            #pragma unroll
            for (int ih = 0; ih < 2; ++ih)
                #pragma unroll
                for (int il = 0; il < 4; ++il)
                    #pragma unroll
                    for (int jl = 0; jl < 4; ++jl)
                        acc[ih][il][jl] = fmaf(aa[ih][il], bbv[jl], acc[ih][il][jl]);
        }
    }
    const int col = n0 + (tx << 2);
    if (col < N) {
        #pragma unroll
        for (int ih = 0; ih < 2; ++ih)
            #pragma unroll
            for (int il = 0; il < 4; ++il) {
                const int row = m0 + (ih << 6) + (ty << 2) + il;
                float4 v = make_float4(acc[ih][il][0], acc[ih][il][1],
                                       acc[ih][il][2], acc[ih][il][3]);
                if (col < split)
                    *(float4*)(out0 + (size_t)row * split + col) = v;
                else
                    *(float4*)(out1 + (size_t)row * (N - split) + (col - split)) = v;
            }
    }
}

// ---------------- causal depthwise conv (k=4) + SiLU ----------------
__global__ __launch_bounds__(256) void conv_kernel(const float* __restrict__ xr,
        const float* __restrict__ cw, const float* __restrict__ cb,
        float* __restrict__ xi) {
    const int g = blockIdx.x * 256 + threadIdx.x;  // < BSZ*NLEN*DINNER
    const int d = g & (DINNER - 1);
    const int n = (g >> 10) & (NLEN - 1);
    const float4 wv = *(const float4*)(cw + d * 4);  // taps k=0..3 -> n-3..n
    const float* p = xr + g;
    float acc = cb[d];
    acc = fmaf(wv.w, p[0], acc);
    if (n >= 1) acc = fmaf(wv.z, p[-DINNER], acc);
    if (n >= 2) acc = fmaf(wv.y, p[-2 * DINNER], acc);
    if (n >= 3) acc = fmaf(wv.x, p[-3 * DINNER], acc);
    xi[g] = acc / (1.f + expf(-acc));
}

// ---------------- dt = softplus(dtr @ W^T + b), one row per block ----------------
__global__ __launch_bounds__(256) void dt_kernel(const float* __restrict__ xdbl,
        const float* __restrict__ W, const float* __restrict__ bias,
        float* __restrict__ dt) {
    const int row = blockIdx.x;  // 0..4095
    __shared__ float r[DTRANK];
    if (threadIdx.x < DTRANK) r[threadIdx.x] = xdbl[(size_t)row * XDBL_W + threadIdx.x];
    __syncthreads();
    #pragma unroll
    for (int q = 0; q < 4; ++q) {
        const int d = (q << 8) + threadIdx.x;
        float acc = bias[d];
        const float* wp = W + (size_t)d * DTRANK;
        #pragma unroll
        for (int j = 0; j < DTRANK; ++j) acc = fmaf(r[j], wp[j], acc);
        dt[(size_t)row * DINNER + d] = (acc > 20.f) ? acc : log1pf(expf(acc));
    }
}

// DPP full-wave (64) f32 sum; result lands in lane 63. Pure VALU, no LDS.
__device__ __forceinline__ float dpp_sum64(float x) {
    x += __int_as_float(__builtin_amdgcn_update_dpp(0, __float_as_int(x), 0x111, 0xf, 0xf, false)); // row_shr:1
    x += __int_as_float(__builtin_amdgcn_update_dpp(0, __float_as_int(x), 0x112, 0xf, 0xf, false)); // row_shr:2
    x += __int_as_float(__builtin_amdgcn_update_dpp(0, __float_as_int(x), 0x114, 0xf, 0xf, false)); // row_shr:4
    x += __int_as_float(__builtin_amdgcn_update_dpp(0, __float_as_int(x), 0x118, 0xf, 0xf, false)); // row_shr:8
    x += __int_as_float(__builtin_amdgcn_update_dpp(0, __float_as_int(x), 0x142, 0xa, 0xf, false)); // row_bcast:15 rows 1,3
    x += __int_as_float(__builtin_amdgcn_update_dpp(0, __float_as_int(x), 0x143, 0xc, 0xf, false)); // row_bcast:31 rows 2,3
    return x;
}

// ---------------- selective scan: one wave per (b,d); lane = state s ----------------
// Per 64-step block: gather dt/u (lane j = step j), broadcast via readlane(j);
// h-update 3 VALU; y via 6-op DPP reduce + readlane(63) + cndmask select.
// y stored transposed yt[b][d][n] with one coalesced 64-wide store per block.
__global__ __launch_bounds__(256) void scan_kernel(const float* __restrict__ dt,
        const float* __restrict__ u, const float* __restrict__ xdbl,
        const float* __restrict__ A_log, float* __restrict__ yt) {
    const int w = (blockIdx.x << 2) + (threadIdx.x >> 6);  // 0..2047
    const int lane = threadIdx.x & 63;
    const int b = w >> 10, d = w & (DINNER - 1);
    const float* dtp = dt + (size_t)b * NLEN * DINNER + d;
    const float* up  = u  + (size_t)b * NLEN * DINNER + d;
    const float* Bb  = xdbl + (size_t)b * NLEN * XDBL_W + DTRANK + lane;
    float* yp = yt + ((size_t)b * DINNER + d) * NLEN;
    // kA = A * log2(e), A = -exp(A_log)
    const float kA = -__builtin_amdgcn_exp2f(A_log[d * DSTATE + lane] * 1.44269504f)
                     * 1.44269504f;
    float h = 0.f;
    for (int n0 = 0; n0 < NLEN; n0 += 64) {
        // lane j holds step n0+j values
        float dtv = dtp[(size_t)(n0 + lane) * DINNER];
        float uv  = up [(size_t)(n0 + lane) * DINNER];
        float dtu = dtv * uv;
        float ybuf = 0.f;
        const float* Bn = Bb + (size_t)n0 * XDBL_W;
        #pragma unroll
        for (int j = 0; j < 64; ++j) {
            const float Bv = Bn[j * XDBL_W];
            const float Cv = Bn[j * XDBL_W + DSTATE];
            const float sdt  = __int_as_float(__builtin_amdgcn_readlane(__float_as_int(dtv), j));
            const float sdtu = __int_as_float(__builtin_amdgcn_readlane(__float_as_int(dtu), j));
            const float dA = __builtin_amdgcn_exp2f(kA * sdt);
            h = fmaf(dA, h, sdtu * Bv);
            float yc = dpp_sum64(h * Cv);
            const float ys = __int_as_float(__builtin_amdgcn_readlane(__float_as_int(yc), 63));
            ybuf = (lane == j) ? ys : ybuf;   // v_cmp + v_cndmask (SGPR src)
        }
        yp[n0 + lane] = ybuf;
    }
}

// ---------------- gate: yg = (yt^T + xi*D) * silu(z) ----------------
__global__ __launch_bounds__(256) void gate_kernel(const float* __restrict__ yt,
        const float* __restrict__ xi, const float* __restrict__ z,
        const float* __restrict__ Dv, float* __restrict__ yg) {
    const int g = blockIdx.x * 256 + threadIdx.x;
    const int d = g & (DINNER - 1);
    const int n = (g >> 10) & (NLEN - 1);
    const int b = g >> 21;
    const float yv = yt[((size_t)b * DINNER + d) * NLEN + n];
    const float zv = z[g];
    yg[g] = fmaf(xi[g], Dv[d], yv) * (zv / (1.f + expf(-zv)));
}

extern "C" void kernel_launch(void* const* d_in, const int* in_sizes, int n_in,
                              void* d_out, int out_size, void* d_ws, size_t ws_size,
                              hipStream_t stream) {
    const float* x         = (const float*)d_in[0];
    const float* norm_w    = (const float*)d_in[1];
    const float* norm_b    = (const float*)d_in[2];
    const float* in_proj_w = (const float*)d_in[3];
    const float* conv_w    = (const float*)d_in[4];
    const float* conv_b    = (const float*)d_in[5];
    const float* x_proj_w  = (const float*)d_in[6];
    const float* dt_proj_w = (const float*)d_in[7];
    const float* dt_proj_b = (const float*)d_in[8];
    const float* A_log     = (const float*)d_in[9];
    const float* Dvec      = (const float*)d_in[10];
    const float* out_proj_w= (const float*)d_in[11];
    float* out = (float*)d_out;
    float* ws  = (float*)d_ws;

    const size_t M4 = (size_t)4 * 1024 * 1024;   // 4M floats = 16MB
    float* xn_dt = ws;                 // xn (2M floats) then reused for dt (4M floats)
    float* xiraw = ws + M4;            // xi pre-conv; later reused for yg
    float* zbuf  = ws + 2 * M4;
    float* xibuf = ws + 3 * M4;        // xi post conv+silu
    float* xdbl  = ws + 4 * M4;        // 4096*160 = 655360 floats
    float* ytbuf = ws + 4 * M4 + (size_t)NROWS * XDBL_W;  // 4M floats
    // total: 21,626,880 floats = 86.5 MB

    ln_kernel<<<NROWS / 4, 256, 0, stream>>>(x, norm_w, norm_b, xn_dt);
    gemm_nt<<<dim3(2048 / 64, NROWS / 128), 256, 0, stream>>>(
        xn_dt, in_proj_w, NROWS, 2048, D_MODEL, xiraw, zbuf, DINNER);
    conv_kernel<<<(BSZ * NLEN * DINNER) / 256, 256, 0, stream>>>(
        xiraw, conv_w, conv_b, xibuf);
    gemm_nt<<<dim3((XDBL_W + 63) / 64, NROWS / 128), 256, 0, stream>>>(
        xibuf, x_proj_w, NROWS, XDBL_W, DINNER, xdbl, nullptr, XDBL_W);
    dt_kernel<<<NROWS, 256, 0, stream>>>(xdbl, dt_proj_w, dt_proj_b, xn_dt);
    scan_kernel<<<(BSZ * DINNER) / 4, 256, 0, stream>>>(
        xn_dt, xibuf, xdbl, A_log, ytbuf);
    gate_kernel<<<(BSZ * NLEN * DINNER) / 256, 256, 0, stream>>>(
        ytbuf, xibuf, zbuf, Dvec, xiraw);
    gemm_nt<<<dim3(D_MODEL / 64, NROWS / 128), 256, 0, stream>>>(
        xiraw, out_proj_w, NROWS, D_MODEL, DINNER, out, nullptr, D_MODEL);
}

// Round 4
// 488.385 us; speedup vs baseline: 2.1322x; 2.1322x over previous
//
#include <hip/hip_runtime.h>

#define D_MODEL 512
#define DINNER  1024
#define DSTATE  64
#define DTRANK  32
#define BSZ     2
#define NLEN    2048
#define NROWS   (BSZ*NLEN)   // 4096
#define XDBL_W  (DTRANK + 2*DSTATE)  // 160

// ---------------- LayerNorm: one wave per row ----------------
__global__ __launch_bounds__(256) void ln_kernel(const float* __restrict__ x,
        const float* __restrict__ w, const float* __restrict__ bvec,
        float* __restrict__ xn) {
    const int wid = threadIdx.x >> 6, lane = threadIdx.x & 63;
    const int row = (blockIdx.x << 2) + wid;
    const float4* xp = (const float4*)(x + (size_t)row * D_MODEL);
    float4 v0 = xp[lane], v1 = xp[lane + 64];
    float s = v0.x + v0.y + v0.z + v0.w + v1.x + v1.y + v1.z + v1.w;
    float q = v0.x*v0.x + v0.y*v0.y + v0.z*v0.z + v0.w*v0.w
            + v1.x*v1.x + v1.y*v1.y + v1.z*v1.z + v1.w*v1.w;
    #pragma unroll
    for (int m = 32; m; m >>= 1) { s += __shfl_xor(s, m); q += __shfl_xor(q, m); }
    const float mean = s * (1.f / D_MODEL);
    const float var  = q * (1.f / D_MODEL) - mean * mean;
    const float rstd = rsqrtf(var + 1e-5f);
    const float4* wp = (const float4*)w;
    const float4* bp = (const float4*)bvec;
    float4 w0 = wp[lane], w1 = wp[lane + 64], b0 = bp[lane], b1 = bp[lane + 64];
    float4 o0, o1;
    o0.x = (v0.x - mean) * rstd * w0.x + b0.x;
    o0.y = (v0.y - mean) * rstd * w0.y + b0.y;
    o0.z = (v0.z - mean) * rstd * w0.z + b0.z;
    o0.w = (v0.w - mean) * rstd * w0.w + b0.w;
    o1.x = (v1.x - mean) * rstd * w1.x + b1.x;
    o1.y = (v1.y - mean) * rstd * w1.y + b1.y;
    o1.z = (v1.z - mean) * rstd * w1.z + b1.z;
    o1.w = (v1.w - mean) * rstd * w1.w + b1.w;
    float4* op = (float4*)(xn + (size_t)row * D_MODEL);
    op[lane] = o0; op[lane + 64] = o1;
}

// ------------- generic NT SGEMM: C(M,N) = A(M,K) * B(N,K)^T -------------
__global__ __launch_bounds__(256) void gemm_nt(const float* __restrict__ A,
        const float* __restrict__ B, int M, int N, int K,
        float* __restrict__ out0, float* __restrict__ out1, int split) {
    __shared__ float sA[8][132];
    __shared__ float sB[8][68];
    const int tid = threadIdx.x;
    const int m0 = blockIdx.y * 128, n0 = blockIdx.x * 64;
    const int lr = tid >> 1, lc = (tid & 1) << 2;
    const int ty = tid >> 4, tx = tid & 15;
    float acc[2][4][4] = {};
    const float* Aptr = A + (size_t)(m0 + lr) * K + lc;
    const bool bvalid = (tid < 128) && (n0 + lr < N);
    const float* Bptr = B + (size_t)(bvalid ? (n0 + lr) : 0) * K + lc;
    float4 av = *(const float4*)Aptr;
    float4 bv = bvalid ? *(const float4*)Bptr : make_float4(0.f, 0.f, 0.f, 0.f);
    for (int k0 = 0; k0 < K; k0 += 8) {
        __syncthreads();
        sA[lc + 0][lr] = av.x; sA[lc + 1][lr] = av.y;
        sA[lc + 2][lr] = av.z; sA[lc + 3][lr] = av.w;
        if (tid < 128) {
            sB[lc + 0][lr] = bv.x; sB[lc + 1][lr] = bv.y;
            sB[lc + 2][lr] = bv.z; sB[lc + 3][lr] = bv.w;
        }
        __syncthreads();
        if (k0 + 8 < K) {
            av = *(const float4*)(Aptr + k0 + 8);
            if (bvalid) bv = *(const float4*)(Bptr + k0 + 8);
        }
        #pragma unroll
        for (int kk = 0; kk < 8; ++kk) {
            float4 a0 = *(const float4*)&sA[kk][ty << 2];
            float4 a1 = *(const float4*)&sA[kk][64 + (ty << 2)];
            float4 bb = *(const float4*)&sB[kk][tx << 2];
            const float aa[2][4] = {{a0.x, a0.y, a0.z, a0.w}, {a1.x, a1.y, a1.z, a1.w}};
            const float bbv[4] = {bb.x, bb.y, bb.z, bb.w};
            #pragma unroll
            for (int ih = 0; ih < 2; ++ih)
                #pragma unroll
                for (int il = 0; il < 4; ++il)
                    #pragma unroll
                    for (int jl = 0; jl < 4; ++jl)
                        acc[ih][il][jl] = fmaf(aa[ih][il], bbv[jl], acc[ih][il][jl]);
        }
    }
    const int col = n0 + (tx << 2);
    if (col < N) {
        #pragma unroll
        for (int ih = 0; ih < 2; ++ih)
            #pragma unroll
            for (int il = 0; il < 4; ++il) {
                const int row = m0 + (ih << 6) + (ty << 2) + il;
                float4 v = make_float4(acc[ih][il][0], acc[ih][il][1],
                                       acc[ih][il][2], acc[ih][il][3]);
                if (col < split)
                    *(float4*)(out0 + (size_t)row * split + col) = v;
                else
                    *(float4*)(out1 + (size_t)row * (N - split) + (col - split)) = v;
            }
    }
}

// ---------------- causal depthwise conv (k=4) + SiLU ----------------
__global__ __launch_bounds__(256) void conv_kernel(const float* __restrict__ xr,
        const float* __restrict__ cw, const float* __restrict__ cb,
        float* __restrict__ xi) {
    const int g = blockIdx.x * 256 + threadIdx.x;  // < BSZ*NLEN*DINNER
    const int d = g & (DINNER - 1);
    const int n = (g >> 10) & (NLEN - 1);
    const float4 wv = *(const float4*)(cw + d * 4);  // taps k=0..3 -> n-3..n
    const float* p = xr + g;
    float acc = cb[d];
    acc = fmaf(wv.w, p[0], acc);
    if (n >= 1) acc = fmaf(wv.z, p[-DINNER], acc);
    if (n >= 2) acc = fmaf(wv.y, p[-2 * DINNER], acc);
    if (n >= 3) acc = fmaf(wv.x, p[-3 * DINNER], acc);
    xi[g] = acc / (1.f + expf(-acc));
}

// ---------------- dt = softplus(dtr @ W^T + b), one row per block ----------------
__global__ __launch_bounds__(256) void dt_kernel(const float* __restrict__ xdbl,
        const float* __restrict__ W, const float* __restrict__ bias,
        float* __restrict__ dt) {
    const int row = blockIdx.x;  // 0..4095
    __shared__ float r[DTRANK];
    if (threadIdx.x < DTRANK) r[threadIdx.x] = xdbl[(size_t)row * XDBL_W + threadIdx.x];
    __syncthreads();
    #pragma unroll
    for (int q = 0; q < 4; ++q) {
        const int d = (q << 8) + threadIdx.x;
        float acc = bias[d];
        const float* wp = W + (size_t)d * DTRANK;
        #pragma unroll
        for (int j = 0; j < DTRANK; ++j) acc = fmaf(r[j], wp[j], acc);
        dt[(size_t)row * DINNER + d] = (acc > 20.f) ? acc : log1pf(expf(acc));
    }
}

// ---------------- selective scan: one wave per (b,d); lane = state s ----------------
// Critical chain = h-FMA only. Per 32-step sub-block:
//  Phase A: lane=s: h = fma(exp2(kA*dt_j), h, dtu_j*B_j[s]); write p[j][s]=h*C_j[s]
//           to LDS (pad 65 -> banks (j+s)%32, 2-way free). dt/dtu broadcast via
//           readlane of gather registers written long before (no hazard stalls).
//  Phase B: lane=(half,n): y_n = sum_s p[n][s] over its 32-s half (conflict-free
//           b32 reads, 4 split accumulators), shfl_xor(32), coalesced store.
__global__ __launch_bounds__(256) void scan_kernel(const float* __restrict__ dt,
        const float* __restrict__ u, const float* __restrict__ xdbl,
        const float* __restrict__ A_log, float* __restrict__ yt) {
    __shared__ float p[4][32][65];
    const int wid = threadIdx.x >> 6;
    const int w = (blockIdx.x << 2) + wid;  // 0..2047
    const int lane = threadIdx.x & 63;
    const int b = w >> 10, d = w & (DINNER - 1);
    const float* dtp = dt + (size_t)b * NLEN * DINNER + d;
    const float* up  = u  + (size_t)b * NLEN * DINNER + d;
    const float* Bb  = xdbl + (size_t)b * NLEN * XDBL_W + DTRANK + lane;
    float* yp = yt + ((size_t)b * DINNER + d) * NLEN;
    const float kA = -__builtin_amdgcn_exp2f(A_log[d * DSTATE + lane] * 1.44269504f)
                     * 1.44269504f;   // A*log2(e)
    float (*pw)[65] = p[wid];
    const int rn = lane & 31;          // phase-B step column
    const int rs = (lane >> 5) << 5;   // phase-B s-base: 0 or 32
    float h = 0.f;
    for (int n0 = 0; n0 < NLEN; n0 += 64) {
        const float dtv = dtp[(size_t)(n0 + lane) * DINNER];
        const float uv  = up [(size_t)(n0 + lane) * DINNER];
        const float dtu = dtv * uv;
        #pragma unroll
        for (int half = 0; half < 2; ++half) {
            const float* Bn = Bb + (size_t)(n0 + 32 * half) * XDBL_W;
            #pragma unroll
            for (int j = 0; j < 32; ++j) {
                const float Bv = Bn[j * XDBL_W];
                const float Cv = Bn[j * XDBL_W + DSTATE];
                const float sdt = __int_as_float(
                    __builtin_amdgcn_readlane(__float_as_int(dtv), 32 * half + j));
                const float sdu = __int_as_float(
                    __builtin_amdgcn_readlane(__float_as_int(dtu), 32 * half + j));
                const float dA = __builtin_amdgcn_exp2f(kA * sdt);
                h = fmaf(dA, h, sdu * Bv);
                pw[j][lane] = h * Cv;
            }
            float y0 = 0.f, y1 = 0.f, y2 = 0.f, y3 = 0.f;
            #pragma unroll
            for (int i = 0; i < 32; i += 4) {
                y0 += pw[rn][rs + i];
                y1 += pw[rn][rs + i + 1];
                y2 += pw[rn][rs + i + 2];
                y3 += pw[rn][rs + i + 3];
            }
            float y = (y0 + y1) + (y2 + y3);
            y += __shfl_xor(y, 32);
            if (lane < 32) yp[n0 + 32 * half + rn] = y;
        }
    }
}

// ---------------- gate: yg = (yt^T + xi*D) * silu(z) ----------------
__global__ __launch_bounds__(256) void gate_kernel(const float* __restrict__ yt,
        const float* __restrict__ xi, const float* __restrict__ z,
        const float* __restrict__ Dv, float* __restrict__ yg) {
    const int g = blockIdx.x * 256 + threadIdx.x;
    const int d = g & (DINNER - 1);
    const int n = (g >> 10) & (NLEN - 1);
    const int b = g >> 21;
    const float yv = yt[((size_t)b * DINNER + d) * NLEN + n];
    const float zv = z[g];
    yg[g] = fmaf(xi[g], Dv[d], yv) * (zv / (1.f + expf(-zv)));
}

extern "C" void kernel_launch(void* const* d_in, const int* in_sizes, int n_in,
                              void* d_out, int out_size, void* d_ws, size_t ws_size,
                              hipStream_t stream) {
    const float* x         = (const float*)d_in[0];
    const float* norm_w    = (const float*)d_in[1];
    const float* norm_b    = (const float*)d_in[2];
    const float* in_proj_w = (const float*)d_in[3];
    const float* conv_w    = (const float*)d_in[4];
    const float* conv_b    = (const float*)d_in[5];
    const float* x_proj_w  = (const float*)d_in[6];
    const float* dt_proj_w = (const float*)d_in[7];
    const float* dt_proj_b = (const float*)d_in[8];
    const float* A_log     = (const float*)d_in[9];
    const float* Dvec      = (const float*)d_in[10];
    const float* out_proj_w= (const float*)d_in[11];
    float* out = (float*)d_out;
    float* ws  = (float*)d_ws;

    const size_t M4 = (size_t)4 * 1024 * 1024;   // 4M floats = 16MB
    float* xn_dt = ws;                 // xn (2M floats) then reused for dt (4M floats)
    float* xiraw = ws + M4;            // xi pre-conv; later reused for yg
    float* zbuf  = ws + 2 * M4;
    float* xibuf = ws + 3 * M4;        // xi post conv+silu
    float* xdbl  = ws + 4 * M4;        // 4096*160 = 655360 floats
    float* ytbuf = ws + 4 * M4 + (size_t)NROWS * XDBL_W;  // 4M floats
    // total: 21,626,880 floats = 86.5 MB

    ln_kernel<<<NROWS / 4, 256, 0, stream>>>(x, norm_w, norm_b, xn_dt);
    gemm_nt<<<dim3(2048 / 64, NROWS / 128), 256, 0, stream>>>(
        xn_dt, in_proj_w, NROWS, 2048, D_MODEL, xiraw, zbuf, DINNER);
    conv_kernel<<<(BSZ * NLEN * DINNER) / 256, 256, 0, stream>>>(
        xiraw, conv_w, conv_b, xibuf);
    gemm_nt<<<dim3((XDBL_W + 63) / 64, NROWS / 128), 256, 0, stream>>>(
        xibuf, x_proj_w, NROWS, XDBL_W, DINNER, xdbl, nullptr, XDBL_W);
    dt_kernel<<<NROWS, 256, 0, stream>>>(xdbl, dt_proj_w, dt_proj_b, xn_dt);
    scan_kernel<<<(BSZ * DINNER) / 4, 256, 0, stream>>>(
        xn_dt, xibuf, xdbl, A_log, ytbuf);
    gate_kernel<<<(BSZ * NLEN * DINNER) / 256, 256, 0, stream>>>(
        ytbuf, xibuf, zbuf, Dvec, xiraw);
    gemm_nt<<<dim3(D_MODEL / 64, NROWS / 128), 256, 0, stream>>>(
        xiraw, out_proj_w, NROWS, D_MODEL, DINNER, out, nullptr, D_MODEL);
}